// Round 4
// baseline (186.566 us; speedup 1.0000x reference)
//
#include <hip/hip_runtime.h>
#include <hip/hip_bf16.h>

#define L 512
#define CS 256
#define CZ 128
#define LN_EPS 1e-5f

typedef _Float16 f16_t;
typedef f16_t f16x8 __attribute__((ext_vector_type(8)));
typedef float f32x4 __attribute__((ext_vector_type(4)));

// ---- Kernel PREP -----------------------------------------------------------
// Per-block (i = blockIdx.x): embed + LN -> s_out, u2 (CHUNK-MAJOR f16:
// u2[c>>3][i][c&7]), zrow = u@W1 + b, zcol = u@W2.
// Spare duties: blocks 0..127 build w3c (chunk-major W3^T f16), blocks
// 128..391 build tab[cp*66+rp] = Ecp[cp] + Erp[rp].
__global__ __launch_bounds__(256) void k_prep(
    const int* __restrict__ seq, const int* __restrict__ cid,
    const int* __restrict__ ridx,
    const float* __restrict__ Eaa, const float* __restrict__ Epos,
    const float* __restrict__ Ech, const float* __restrict__ lnw,
    const float* __restrict__ lnb, const float* __restrict__ Wp,
    const float* __restrict__ bp, const float* __restrict__ Ecp,
    const float* __restrict__ Erp,
    float* __restrict__ s_out, f16_t* __restrict__ u2,
    float* __restrict__ zrow, float* __restrict__ zcol,
    f16_t* __restrict__ w3c, float* __restrict__ tab)
{
    __shared__ float su[CS];
    __shared__ float red[8];
    const int i = blockIdx.x;
    const int c = threadIdx.x;

    if (i < 128) {
        w3c[(c >> 3) * (CZ * 8) + i * 8 + (c & 7)] = (f16_t)Wp[(2 * CS + c) * CZ + i];
    } else if (i < 128 + 264) {
        const int b2 = i - 128;
        if (c < CZ)
            tab[b2 * CZ + c] = Ecp[(b2 / 66) * CZ + c] + Erp[(b2 % 66) * CZ + c];
    }

    const int sq = seq[i], ri = ridx[i], ci = cid[i];
    const float v = Eaa[sq * CS + c] + Epos[ri * CS + c] + Ech[ci * CS + c];
    s_out[i * CS + c] = v;

    float s1 = v, s2 = v * v;
    #pragma unroll
    for (int o = 32; o > 0; o >>= 1) {
        s1 += __shfl_down(s1, o, 64);
        s2 += __shfl_down(s2, o, 64);
    }
    const int wv = c >> 6, lane = c & 63;
    if (lane == 0) { red[wv * 2] = s1; red[wv * 2 + 1] = s2; }
    __syncthreads();
    const float S  = red[0] + red[2] + red[4] + red[6];
    const float SS = red[1] + red[3] + red[5] + red[7];
    const float mu  = S * (1.0f / CS);
    const float var = SS * (1.0f / CS) - mu * mu;
    const float rs  = rsqrtf(var + LN_EPS);
    const float u   = (v - mu) * rs * lnw[c] + lnb[c];
    u2[(c >> 3) * (L * 8) + i * 8 + (c & 7)] = (f16_t)u;
    su[c] = u;
    __syncthreads();

    const int z = c & 127;
    const int half = c >> 7;  // 0 -> zrow(W1), 1 -> zcol(W2)
    const float* W = Wp + half * CS * CZ + z;
    float a0 = 0, a1 = 0, a2 = 0, a3 = 0;
    #pragma unroll 8
    for (int cc = 0; cc < CS; cc += 4) {
        a0 += su[cc + 0] * W[(cc + 0) * CZ];
        a1 += su[cc + 1] * W[(cc + 1) * CZ];
        a2 += su[cc + 2] * W[(cc + 2) * CZ];
        a3 += su[cc + 3] * W[(cc + 3) * CZ];
    }
    const float acc = (a0 + a1) + (a2 + a3);
    if (half) zcol[i * CZ + z] = acc;
    else      zrow[i * CZ + z] = acc + bp[z];
}

// ---- Kernel PAIR (v5: epilogue fused into MFMA C-init) ---------------------
// v4 residue: wall ~120K cyc/CU vs max-pipe 52K (stores) -> ~70K cyc of
// exposed latency. Sources: (a) each pass ended with 18 dependent L2 loads
// (zrow/zcol/tab) serialized between MFMA chain and stores; (b) all operand
// loads sat after the barrier. v5: acc is INITIALIZED to zrow+zcol+tab
// (mathematically identical, f32 add reorder << 0.03 tol):
//   - pass-0 init loads issue BEFORE the barrier (hide under staging drain)
//   - each pass's epilogue is pure fire-and-forget stores, issued the cycle
//     the MFMA chain retires
//   - pass-1 init loads issue right after pass-0 stores, hiding under
//     pass-1's ds_read/MFMA chain
// s_setprio(1) wraps the MFMA cluster: waves are barrier-free and
// phase-staggered here (the attn-like regime where setprio measured +4-7%,
// not the lockstep-GEMM null). Tiling/LDS identical to v4 (conflict-free).
__global__ __launch_bounds__(512, 4) void k_pair(
    const f16_t* __restrict__ u2, const f16_t* __restrict__ w3c,
    const float* __restrict__ zrow, const float* __restrict__ zcol,
    const float* __restrict__ tab,
    const int* __restrict__ cid, const int* __restrict__ ridx,
    float* __restrict__ zout)
{
    __shared__ f16_t lds[(1024 + 256) * 8];  // u_j tile (16KB) + u_i tile (4KB)
    f16x8* lj = (f16x8*)lds;
    f16x8* li = ((f16x8*)lds) + 1024;

    const int t = threadIdx.x;
    const int lane = t & 63, wave = t >> 6;
    const int m = lane & 15, q = lane >> 4;
    const int j0 = blockIdx.x * 32, i0 = blockIdx.y * 8;
    const int jh = wave & 1;          // j-half: 16 j's
    const int ih = (wave >> 1) & 1;   // i-half: 4 i's
    const int zh = wave >> 2;         // z-half: 64 z's (2 passes of 32)
    const int jm = j0 + jh * 16 + m;
    const int ib = ih * 4;            // local i base
    const int zb = zh * 64;

    const f16x8* pu = (const f16x8*)u2;      // [32 chunks][512 rows]
    const f16x8* pw = (const f16x8*)w3c;     // [32 chunks][128 z]

    // stage LDS tiles (contiguous src + dst; R0-verified conflict-free)
    if (t < 256) li[t] = pu[(t >> 3) * L + i0 + (t & 7)];   // t = ch*8 + ii
    #pragma unroll
    for (int rep = 0; rep < 2; ++rep) {
        const int un = rep * 512 + t;                       // un = ch*32 + jj
        lj[un] = pu[(un >> 5) * L + j0 + (un & 31)];
    }

    // epilogue index math, hoisted (independent of LDS)
    const int cj = cid[jm], rj = ridx[jm];
    int xx[4];
    #pragma unroll
    for (int ii = 0; ii < 4; ++ii) {
        const int i = i0 + ib + ii;
        const int ci = cid[i], ri = ridx[i];
        int d = ri - rj; d = d < -32 ? -32 : (d > 32 ? 32 : d);
        xx[ii] = ((ci * 2 + cj) * 66) + ((ci == cj) ? (d + 32) : 65);
    }

    // pass-0 acc C-init (L2 loads issued PRE-barrier: hide under staging)
    f32x4 acc[4][2];
    {
        const int zo0 = zb + q * 4, zo1 = zb + 16 + q * 4;
        const f32x4 ZC0 = *(const f32x4*)&zcol[jm * CZ + zo0];
        const f32x4 ZC1 = *(const f32x4*)&zcol[jm * CZ + zo1];
        #pragma unroll
        for (int ii = 0; ii < 4; ++ii) {
            const int i = i0 + ib + ii;
            acc[ii][0] = *(const f32x4*)&zrow[i * CZ + zo0] + ZC0
                       + *(const f32x4*)&tab[xx[ii] * CZ + zo0];
            acc[ii][1] = *(const f32x4*)&zrow[i * CZ + zo1] + ZC1
                       + *(const f32x4*)&tab[xx[ii] * CZ + zo1];
        }
    }

    __syncthreads();

    #pragma unroll 1
    for (int pass = 0; pass < 2; ++pass) {
        const int z0 = zb + pass * 32;

        __builtin_amdgcn_s_setprio(1);
        #pragma unroll 2
        for (int k32 = 0; k32 < 8; ++k32) {
            const int cb = k32 * 4 + q;               // c-chunk index
            const f16x8 A0 = pw[cb * CZ + z0 + m];        // W3^T, L2-resident
            const f16x8 A1 = pw[cb * CZ + z0 + 16 + m];
            const f16x8 ujv = lj[cb * 32 + jh * 16 + m];  // conflict-free b128
            #pragma unroll
            for (int ii = 0; ii < 4; ++ii) {
                const f16x8 B = li[cb * 8 + ib + ii] * ujv; // bcast + 4 v_pk
                acc[ii][0] = __builtin_amdgcn_mfma_f32_16x16x32_f16(A0, B, acc[ii][0], 0, 0, 0);
                acc[ii][1] = __builtin_amdgcn_mfma_f32_16x16x32_f16(A1, B, acc[ii][1], 0, 0, 0);
            }
        }
        __builtin_amdgcn_s_setprio(0);

        // pure store epilogue (fire-and-forget; no dependent loads)
        const int zo0 = z0 + q * 4;
        const int zo1 = z0 + 16 + q * 4;
        #pragma unroll
        for (int ii = 0; ii < 4; ++ii) {
            const int i = i0 + ib + ii;
            float* r_o = zout + ((size_t)i * L + jm) * CZ;
            *(f32x4*)(r_o + zo0) = acc[ii][0];
            *(f32x4*)(r_o + zo1) = acc[ii][1];
        }

        // next-pass C-init: issues right after stores, hides under next
        // pass's ds_read + MFMA chain
        if (pass == 0) {
            const int zn0 = zb + 32 + q * 4, zn1 = zb + 48 + q * 4;
            const f32x4 ZC0 = *(const f32x4*)&zcol[jm * CZ + zn0];
            const f32x4 ZC1 = *(const f32x4*)&zcol[jm * CZ + zn1];
            #pragma unroll
            for (int ii = 0; ii < 4; ++ii) {
                const int i = i0 + ib + ii;
                acc[ii][0] = *(const f32x4*)&zrow[i * CZ + zn0] + ZC0
                           + *(const f32x4*)&tab[xx[ii] * CZ + zn0];
                acc[ii][1] = *(const f32x4*)&zrow[i * CZ + zn1] + ZC1
                           + *(const f32x4*)&tab[xx[ii] * CZ + zn1];
            }
        }
    }
}

extern "C" void kernel_launch(void* const* d_in, const int* in_sizes, int n_in,
                              void* d_out, int out_size, void* d_ws, size_t ws_size,
                              hipStream_t stream) {
    const int*   seq  = (const int*)d_in[0];
    const int*   cid  = (const int*)d_in[1];
    const int*   ridx = (const int*)d_in[2];
    const float* Eaa  = (const float*)d_in[3];
    const float* Epos = (const float*)d_in[4];
    const float* Ech  = (const float*)d_in[5];
    const float* Ecp  = (const float*)d_in[6];
    const float* Erp  = (const float*)d_in[7];
    const float* Wp   = (const float*)d_in[8];
    const float* bp   = (const float*)d_in[9];
    const float* lnw  = (const float*)d_in[10];
    const float* lnb  = (const float*)d_in[11];

    float* out   = (float*)d_out;
    float* s_out = out;
    float* zout  = out + L * CS;

    char* ws = (char*)d_ws;
    f16_t* u2   = (f16_t*)ws;                 // 256 KB, chunk-major
    f16_t* w3c  = (f16_t*)(ws + 262144);      // 64 KB, chunk-major
    float* zrow = (float*)(ws + 327680);      // 256 KB
    float* zcol = (float*)(ws + 589824);      // 256 KB
    float* tab  = (float*)(ws + 851968);      // 132 KB

    hipLaunchKernelGGL(k_prep, dim3(L), dim3(256), 0, stream,
                       seq, cid, ridx, Eaa, Epos, Ech, lnw, lnb, Wp, bp,
                       Ecp, Erp, s_out, u2, zrow, zcol, w3c, tab);
    hipLaunchKernelGGL(k_pair, dim3(16, 64), dim3(512), 0, stream,
                       u2, w3c, zrow, zcol, tab, cid, ridx, zout);
}